// Round 24
// baseline (12539.838 us; speedup 1.0000x reference)
//
#include <hip/hip_runtime.h>

// Farthest point sampling, B=32, N=32768, npoint=4096.
// R24 = R23 with the compile fix: DPP ctrl codes must be LITERAL constants
// -> the 4-stage combine is a macro with literal ctrls (0xB1, 0x4E, 0x141,
// 0x140), not a loop variable.
// Design (R23): ONE barrier + ZERO atomics reduce, DPP only:
//  per wave: 6-stage DPP fmax -> readlane(63) bcast Mwb;
//            candidates bi (best==Mwb, else UINT_MAX) -> 6-stage DPP u32min
//            -> wave first-occurrence index iw (lane 63);
//  lane63 plain-writes (Mwb, iw) to s_wv/s_wi[k&1][wv];  ONE __syncthreads;
//  all lanes read slot (tid&15) (4-lane bcast) -> 4-stage row-butterfly
//  DPP combine (max val, tie -> min idx) -> every thread knows w; waves
//  proceed INDEPENDENTLY to the centroid load (latency overlaps; no
//  second barrier, no slot resets).
// WAR safety: parity double-buffer; barrier of step k+1 separates step-k
// reads from step-k+2 writes.
// First-occurrence argmax: per-lane lc (ascending, strict >), wave min-bi,
// block max-val/min-idx == numpy argmax. PASSING arithmetic (R6,
// bit-exact): d = fmaf(dz,dz, fmaf(dx,dx, dy*dy)), contract(off), fminf.
// Output float32: idx then coords.

#define BATCH  32
#define NPTS   32768
#define NPOINT 4096
#define NT     1024
#define NCH    16            // chunks of 2: 32 points per thread

#define DPP1(x, ctrl, rm) __builtin_amdgcn_update_dpp((x), (x), (ctrl), (rm), 0xf, false)

__device__ __forceinline__ float wave_max_dpp(float v) {
    unsigned int u = __float_as_uint(v);
    u = __float_as_uint(fmaxf(__uint_as_float(u), __uint_as_float(DPP1(u, 0xB1, 0xf))));
    u = __float_as_uint(fmaxf(__uint_as_float(u), __uint_as_float(DPP1(u, 0x4E, 0xf))));
    u = __float_as_uint(fmaxf(__uint_as_float(u), __uint_as_float(DPP1(u, 0x141, 0xf))));
    u = __float_as_uint(fmaxf(__uint_as_float(u), __uint_as_float(DPP1(u, 0x140, 0xf))));
    u = __float_as_uint(fmaxf(__uint_as_float(u), __uint_as_float(DPP1(u, 0x142, 0xa))));
    u = __float_as_uint(fmaxf(__uint_as_float(u), __uint_as_float(DPP1(u, 0x143, 0xc))));
    return __uint_as_float(u);   // lane 63 = wave max
}

__device__ __forceinline__ unsigned int wave_min_dpp(unsigned int u) {
    unsigned int t;
    t = DPP1(u, 0xB1, 0xf);  u = (t < u) ? t : u;
    t = DPP1(u, 0x4E, 0xf);  u = (t < u) ? t : u;
    t = DPP1(u, 0x141, 0xf); u = (t < u) ? t : u;
    t = DPP1(u, 0x140, 0xf); u = (t < u) ? t : u;
    t = DPP1(u, 0x142, 0xa); u = (t < u) ? t : u;
    t = DPP1(u, 0x143, 0xc); u = (t < u) ? t : u;
    return u;                // lane 63 = wave min
}

// One combine stage with LITERAL ctrl: max val, tie -> min idx.
#define COMBINE_STAGE(CTRL)                                                   \
    do {                                                                      \
        const unsigned int ovu = DPP1(__float_as_uint(v), (CTRL), 0xf);       \
        const unsigned int ox  = DPP1(x, (CTRL), 0xf);                        \
        const float ov = __uint_as_float(ovu);                                \
        const bool take = (ov > v) || (ov == v && ox < x);                    \
        v = take ? ov : v;                                                    \
        x = take ? ox : x;                                                    \
    } while (0)

__global__ __launch_bounds__(NT, 1)
__attribute__((amdgpu_num_vgpr(128)))
void fps_kernel(
    const float* __restrict__ xyz,   // [B, N, 3] float32
    float* __restrict__ out_idx,     // [B, NPOINT]
    float* __restrict__ out_xyz)     // [B, NPOINT, 3]
{
#pragma clang fp contract(off)
    __shared__ float pz_lds[NPTS];               // 128 KB static
    __shared__ float        s_wv[2][16];         // wave max value
    __shared__ unsigned int s_wi[2][16];         // wave argmin index

    const int b   = blockIdx.x;
    const int tid = threadIdx.x;
    const float* base = xyz + (size_t)b * NPTS * 3;

    float px[NCH * 2], py[NCH * 2], dist[NCH * 2];
#pragma unroll
    for (int c = 0; c < NCH; ++c) {
#pragma unroll
        for (int j = 0; j < 2; ++j) {
            const int i = c * 2 + j;
            const int g = c * 2048 + 2 * tid + j;
            px[i] = base[g * 3 + 0];
            py[i] = base[g * 3 + 1];
            pz_lds[g] = base[g * 3 + 2];
            dist[i] = 1e10f;
        }
    }
    __syncthreads();                       // pz_lds ready

    int w = 1;   // RAN=False seed
    int p = 0;   // slot parity k&1

    for (int k = 0; k < NPOINT; ++k) {
        // Broadcast centroid from global (same addr across lanes, L2-hot).
        const float cx = base[w * 3 + 0];
        const float cy = base[w * 3 + 1];
        const float cz = base[w * 3 + 2];
        if (tid == 0) {
            out_idx[(size_t)b * NPOINT + k] = (float)w;
            float* o = out_xyz + ((size_t)b * NPOINT + k) * 3;
            o[0] = cx; o[1] = cy; o[2] = cz;
        }
        if (k == NPOINT - 1) break;

        // Distance update + per-thread first-occurrence argmax.
        float best = -1.0f;
        int   lc   = 63;
#pragma unroll
        for (int c = 0; c < NCH; ++c) {
            const float2 zz = *(const float2*)&pz_lds[c * 2048 + 2 * tid];
            const float pzv[2] = { zz.x, zz.y };
#pragma unroll
            for (int j = 0; j < 2; ++j) {
                const int i = c * 2 + j;
                const float dx = px[i] - cx;
                const float dy = py[i] - cy;
                const float dz = pzv[j] - cz;
                const float d  = fmaf(dz, dz, fmaf(dx, dx, dy * dy));
                const float nd = fminf(dist[i], d);
                dist[i] = nd;
                if (nd > best) { best = nd; lc = 2 * c + j; }
            }
        }

        // Wave reduce via DPP: value max, then first-occurrence index min.
        const float Mw = wave_max_dpp(best);
        const float Mwb = __uint_as_float(
            __builtin_amdgcn_readlane(__float_as_uint(Mw), 63));
        unsigned int bi = 0xffffffffu;
        if (best == Mwb)
            bi = (unsigned int)((lc >> 1) * 2048 + 2 * tid + (lc & 1));
        const unsigned int iw = wave_min_dpp(bi);

        if ((tid & 63) == 63) {            // lane 63 publishes (plain write)
            s_wv[p][tid >> 6] = Mwb;
            s_wi[p][tid >> 6] = iw;
        }
        __syncthreads();                   // ONLY barrier of the step

        // All lanes: read slot (tid&15), 4-stage row-butterfly combine;
        // all 16 lanes of each row end with the block winner.
        float        v = s_wv[p][tid & 15];
        unsigned int x = s_wi[p][tid & 15];
        COMBINE_STAGE(0xB1);
        COMBINE_STAGE(0x4E);
        COMBINE_STAGE(0x141);
        COMBINE_STAGE(0x140);
        w = (int)x;
        p ^= 1;
    }
}

extern "C" void kernel_launch(void* const* d_in, const int* in_sizes, int n_in,
                              void* d_out, int out_size, void* d_ws, size_t ws_size,
                              hipStream_t stream) {
    const float* xyz = (const float*)d_in[0];
    float* out = (float*)d_out;
    float* out_idx = out;                              // B*NPOINT floats
    float* out_xyz = out + (size_t)BATCH * NPOINT;     // B*NPOINT*3 floats

    fps_kernel<<<BATCH, NT, 0, stream>>>(xyz, out_idx, out_xyz);
}

// Round 25
// 8143.609 us; speedup vs baseline: 1.5398x; 1.5398x over previous
//
#include <hip/hip_runtime.h>

// Farthest point sampling, B=32, N=32768, npoint=4096.
// R25: make the register state FIT the 64-arch-VGPR class natively.
// 18 rounds showed: 1024-thread blocks always get 64 arch VGPRs; px/py/dist
// (96 floats) never fit -> AGPR parking + v_accvgpr copy tax (~2x issue).
// Fix: keep ONLY dist[32] in registers (~50 live regs). x,y stream from L2:
// a prep kernel packs xy as float2[B][N] into d_ws (8MB); the inner loop
// reads one coalesced float4 (= 2 points' xy) per chunk. Per-XCD working
// set = 4 blocks x 256KB = 1MB -> L2-resident; ~2500cyc/step of L2 traffic
// overlaps ~2560cyc VALU issue. z stays in static 128KB LDS. Centroid xy =
// ws load, z = LDS read (xyz unused after setup).
// Reduce = R22's proven chassis, byte-identical: DPP wave max (lane 63) ->
// 32-bit LDS atomicMax -> B1 -> candidates (best==M) atomicMin first-
// achieving index -> B2 -> 3-slot rotation reset. Numpy first-occurrence
// argmax preserved (ascending strict-> lc scan; min index among candidates).
// PASSING arithmetic (R6, bit-exact): d = fmaf(dz,dz, fmaf(dx,dx, dy*dy)),
// contract(off), fminf chain. Output float32: idx then coords.

#define BATCH  32
#define NPTS   32768
#define NPOINT 4096
#define NT     1024
#define NCH    16            // chunks of 2: 32 points per thread
#define WS_NEEDED ((size_t)BATCH * NPTS * 8)   // float2 xy per point = 8MB

#define DPP1(x, ctrl, rm) __builtin_amdgcn_update_dpp((x), (x), (ctrl), (rm), 0xf, false)

__device__ __forceinline__ float wave_max_dpp(float v) {
    unsigned int u = __float_as_uint(v);
    u = __float_as_uint(fmaxf(__uint_as_float(u), __uint_as_float(DPP1(u, 0xB1, 0xf))));
    u = __float_as_uint(fmaxf(__uint_as_float(u), __uint_as_float(DPP1(u, 0x4E, 0xf))));
    u = __float_as_uint(fmaxf(__uint_as_float(u), __uint_as_float(DPP1(u, 0x141, 0xf))));
    u = __float_as_uint(fmaxf(__uint_as_float(u), __uint_as_float(DPP1(u, 0x140, 0xf))));
    u = __float_as_uint(fmaxf(__uint_as_float(u), __uint_as_float(DPP1(u, 0x142, 0xa))));
    u = __float_as_uint(fmaxf(__uint_as_float(u), __uint_as_float(DPP1(u, 0x143, 0xc))));
    return __uint_as_float(u);   // lane 63 = wave max
}

// ---- prep: pack xy as float2[B][N] into ws (one-time, ~10us) ----
__global__ __launch_bounds__(256) void pack_xy(
    const float* __restrict__ xyz, float2* __restrict__ ws)
{
    const int i = blockIdx.x * 256 + threadIdx.x;   // 0 .. B*N-1
    ws[i] = make_float2(xyz[(size_t)i * 3 + 0], xyz[(size_t)i * 3 + 1]);
}

__global__ __launch_bounds__(NT, 1) void fps_kernel(
    const float* __restrict__ xyz,    // [B, N, 3] (setup only)
    const float2* __restrict__ wsxy,  // [B, N] packed xy
    float* __restrict__ out_idx,      // [B, NPOINT]
    float* __restrict__ out_xyz)      // [B, NPOINT, 3]
{
#pragma clang fp contract(off)
    __shared__ float pz_lds[NPTS];               // 128 KB static
    __shared__ unsigned int s_val[3];            // dist bits (>=0, monotone)
    __shared__ int s_idx[3];                     // winning global index

    const int b   = blockIdx.x;
    const int tid = threadIdx.x;
    const float* base = xyz + (size_t)b * NPTS * 3;
    const float2* xy  = wsxy + (size_t)b * NPTS;
    const float4* xy4 = (const float4*)xy;       // 2 points per float4

    float dist[NCH * 2];
#pragma unroll
    for (int c = 0; c < NCH; ++c) {
#pragma unroll
        for (int j = 0; j < 2; ++j) {
            const int g = c * 2048 + 2 * tid + j;
            pz_lds[g] = base[g * 3 + 2];
            dist[c * 2 + j] = 1e10f;
        }
    }
    if (tid == 0) {
        s_val[0] = 0u; s_val[1] = 0u; s_val[2] = 0u;
        s_idx[0] = 0x7fffffff; s_idx[1] = 0x7fffffff; s_idx[2] = 0x7fffffff;
    }
    __syncthreads();                       // pz_lds + slots ready

    int w = 1;   // RAN=False seed
    int p = 0;   // rotating slot index k%3

    for (int k = 0; k < NPOINT; ++k) {
        // Centroid: xy from ws (L2, same addr -> broadcast), z from LDS.
        const float2 cxy = xy[w];
        const float cz = pz_lds[w];
        const float cx = cxy.x, cy = cxy.y;
        if (tid == 0) {
            out_idx[(size_t)b * NPOINT + k] = (float)w;
            float* o = out_xyz + ((size_t)b * NPOINT + k) * 3;
            o[0] = cx; o[1] = cy; o[2] = cz;
        }

        // Distance update + per-thread first-occurrence argmax.
        float best = -1.0f;
        int   lc   = 63;
#pragma unroll
        for (int c = 0; c < NCH; ++c) {
            const float4 v  = xy4[c * 1024 + tid];   // x0 y0 x1 y1 (L2)
            const float2 zz = *(const float2*)&pz_lds[c * 2048 + 2 * tid];
            {   // j = 0
                const float dx = v.x - cx;
                const float dy = v.y - cy;
                const float dz = zz.x - cz;
                const float d  = fmaf(dz, dz, fmaf(dx, dx, dy * dy));
                const float nd = fminf(dist[c * 2 + 0], d);
                dist[c * 2 + 0] = nd;
                if (nd > best) { best = nd; lc = 2 * c + 0; }
            }
            {   // j = 1
                const float dx = v.z - cx;
                const float dy = v.w - cy;
                const float dz = zz.y - cz;
                const float d  = fmaf(dz, dz, fmaf(dx, dx, dy * dy));
                const float nd = fminf(dist[c * 2 + 1], d);
                dist[c * 2 + 1] = nd;
                if (nd > best) { best = nd; lc = 2 * c + 1; }
            }
        }

        // Phase A: value-only wave max via DPP; lane 63 publishes.
        const float m = wave_max_dpp(best);
        if ((tid & 63) == 63)
            atomicMax(&s_val[p], __float_as_uint(m));
        __syncthreads();                   // B1: block max known
        const float M = __uint_as_float(s_val[p]);

        // Phase B: candidates (best==M) publish first-achieving index.
        if (best == M) {
            const int bi = (lc >> 1) * 2048 + 2 * tid + (lc & 1);
            atomicMin(&s_idx[p], bi);
        }
        __syncthreads();                   // B2: winning index known
        w = s_idx[p];
        // Reset slot for step k+2 (barriers of step k+1 order this write
        // before that slot's next atomics; its readers finished at k-1).
        const int pn2 = (p >= 1) ? (p - 1) : 2;   // (k+2)%3
        if (tid == 0) { s_val[pn2] = 0u; s_idx[pn2] = 0x7fffffff; }
        p = (p == 2) ? 0 : (p + 1);
    }
}

// ---------- fallback (R22, proven 8.76ms): used only if ws too small ----
__global__ __launch_bounds__(NT, 1)
__attribute__((amdgpu_num_vgpr(128)))
void fps_fallback(
    const float* __restrict__ xyz, float* __restrict__ out_idx,
    float* __restrict__ out_xyz)
{
#pragma clang fp contract(off)
    __shared__ float pz_lds[NPTS];
    __shared__ unsigned int s_val[3];
    __shared__ int s_idx[3];
    const int b = blockIdx.x, tid = threadIdx.x;
    const float* base = xyz + (size_t)b * NPTS * 3;
    float px[NCH * 2], py[NCH * 2], dist[NCH * 2];
#pragma unroll
    for (int c = 0; c < NCH; ++c)
#pragma unroll
        for (int j = 0; j < 2; ++j) {
            const int i = c * 2 + j, g = c * 2048 + 2 * tid + j;
            px[i] = base[g * 3 + 0]; py[i] = base[g * 3 + 1];
            pz_lds[g] = base[g * 3 + 2]; dist[i] = 1e10f;
        }
    if (tid == 0) {
        s_val[0] = 0u; s_val[1] = 0u; s_val[2] = 0u;
        s_idx[0] = 0x7fffffff; s_idx[1] = 0x7fffffff; s_idx[2] = 0x7fffffff;
    }
    __syncthreads();
    int w = 1, p = 0;
    for (int k = 0; k < NPOINT; ++k) {
        const float cx = base[w * 3 + 0], cy = base[w * 3 + 1],
                    cz = base[w * 3 + 2];
        if (tid == 0) {
            out_idx[(size_t)b * NPOINT + k] = (float)w;
            float* o = out_xyz + ((size_t)b * NPOINT + k) * 3;
            o[0] = cx; o[1] = cy; o[2] = cz;
        }
        float best = -1.0f; int lc = 63;
#pragma unroll
        for (int c = 0; c < NCH; ++c) {
            const float2 zz = *(const float2*)&pz_lds[c * 2048 + 2 * tid];
            const float pzv[2] = { zz.x, zz.y };
#pragma unroll
            for (int j = 0; j < 2; ++j) {
                const int i = c * 2 + j;
                const float dx = px[i] - cx, dy = py[i] - cy,
                            dz = pzv[j] - cz;
                const float d  = fmaf(dz, dz, fmaf(dx, dx, dy * dy));
                const float nd = fminf(dist[i], d);
                dist[i] = nd;
                if (nd > best) { best = nd; lc = 2 * c + j; }
            }
        }
        const float m = wave_max_dpp(best);
        if ((tid & 63) == 63) atomicMax(&s_val[p], __float_as_uint(m));
        __syncthreads();
        const float M = __uint_as_float(s_val[p]);
        if (best == M) {
            const int bi = (lc >> 1) * 2048 + 2 * tid + (lc & 1);
            atomicMin(&s_idx[p], bi);
        }
        __syncthreads();
        w = s_idx[p];
        const int pn2 = (p >= 1) ? (p - 1) : 2;
        if (tid == 0) { s_val[pn2] = 0u; s_idx[pn2] = 0x7fffffff; }
        p = (p == 2) ? 0 : (p + 1);
    }
}

extern "C" void kernel_launch(void* const* d_in, const int* in_sizes, int n_in,
                              void* d_out, int out_size, void* d_ws, size_t ws_size,
                              hipStream_t stream) {
    const float* xyz = (const float*)d_in[0];
    float* out = (float*)d_out;
    float* out_idx = out;                              // B*NPOINT floats
    float* out_xyz = out + (size_t)BATCH * NPOINT;     // B*NPOINT*3 floats

    if (ws_size >= WS_NEEDED) {
        float2* wsxy = (float2*)d_ws;
        pack_xy<<<(BATCH * NPTS) / 256, 256, 0, stream>>>(xyz, wsxy);
        fps_kernel<<<BATCH, NT, 0, stream>>>(xyz, wsxy, out_idx, out_xyz);
    } else {
        fps_fallback<<<BATCH, NT, 0, stream>>>(xyz, out_idx, out_xyz);
    }
}

// Round 26
// 8055.785 us; speedup vs baseline: 1.5566x; 1.0109x over previous
//
#include <hip/hip_runtime.h>

// Farthest point sampling, B=32, N=32768, npoint=4096.
// R26 = R25 (8.14ms, VGPR=60, xy streamed from L2 ws, z in 128KB LDS)
// with ONE change: value-only inner loop.
//  - inner loop: best = fmaxf(best, nd) (1 op) instead of tracked (best,lc)
//    (cmp + 2 cndmask). ~10 -> ~8 inst/pt.
//  - index recovered in phase B by R20's proven CONSTANT-INDEX rescan:
//    candidates (best==M, ~1 thread/block) scan dist[31..0] for the first
//    ==M (exec-masked; s_cbranch_execz skips candidate-free waves), then
//    atomicMin the global index. First-occurrence preserved: smallest i
//    <-> smallest global index per thread; min across candidates = numpy
//    argmax. No runtime indexing -> no scratch demotion (rule #20).
// Discriminates the regime: issue-bound -> ~7.3ms; L2->L1-path-bound ->
// neutral (then next round cuts bytes).
// Reduce chassis (R22, proven): DPP wave max (lane63) -> 32-bit LDS
// atomicMax -> B1 -> phase B atomicMin -> B2 -> 3-slot rotation reset.
// PASSING arithmetic (R6, bit-exact): d = fmaf(dz,dz, fmaf(dx,dx, dy*dy)),
// contract(off), fminf chain. Output float32: idx then coords.

#define BATCH  32
#define NPTS   32768
#define NPOINT 4096
#define NT     1024
#define NCH    16            // chunks of 2: 32 points per thread
#define WS_NEEDED ((size_t)BATCH * NPTS * 8)   // float2 xy per point = 8MB

#define DPP1(x, ctrl, rm) __builtin_amdgcn_update_dpp((x), (x), (ctrl), (rm), 0xf, false)

__device__ __forceinline__ float wave_max_dpp(float v) {
    unsigned int u = __float_as_uint(v);
    u = __float_as_uint(fmaxf(__uint_as_float(u), __uint_as_float(DPP1(u, 0xB1, 0xf))));
    u = __float_as_uint(fmaxf(__uint_as_float(u), __uint_as_float(DPP1(u, 0x4E, 0xf))));
    u = __float_as_uint(fmaxf(__uint_as_float(u), __uint_as_float(DPP1(u, 0x141, 0xf))));
    u = __float_as_uint(fmaxf(__uint_as_float(u), __uint_as_float(DPP1(u, 0x140, 0xf))));
    u = __float_as_uint(fmaxf(__uint_as_float(u), __uint_as_float(DPP1(u, 0x142, 0xa))));
    u = __float_as_uint(fmaxf(__uint_as_float(u), __uint_as_float(DPP1(u, 0x143, 0xc))));
    return __uint_as_float(u);   // lane 63 = wave max
}

// ---- prep: pack xy as float2[B][N] into ws (one-time, ~10us) ----
__global__ __launch_bounds__(256) void pack_xy(
    const float* __restrict__ xyz, float2* __restrict__ ws)
{
    const int i = blockIdx.x * 256 + threadIdx.x;   // 0 .. B*N-1
    ws[i] = make_float2(xyz[(size_t)i * 3 + 0], xyz[(size_t)i * 3 + 1]);
}

__global__ __launch_bounds__(NT, 1) void fps_kernel(
    const float* __restrict__ xyz,    // [B, N, 3] (setup only)
    const float2* __restrict__ wsxy,  // [B, N] packed xy
    float* __restrict__ out_idx,      // [B, NPOINT]
    float* __restrict__ out_xyz)      // [B, NPOINT, 3]
{
#pragma clang fp contract(off)
    __shared__ float pz_lds[NPTS];               // 128 KB static
    __shared__ unsigned int s_val[3];            // dist bits (>=0, monotone)
    __shared__ int s_idx[3];                     // winning global index

    const int b   = blockIdx.x;
    const int tid = threadIdx.x;
    const float* base = xyz + (size_t)b * NPTS * 3;
    const float2* xy  = wsxy + (size_t)b * NPTS;
    const float4* xy4 = (const float4*)xy;       // 2 points per float4

    float dist[NCH * 2];
#pragma unroll
    for (int c = 0; c < NCH; ++c) {
#pragma unroll
        for (int j = 0; j < 2; ++j) {
            const int g = c * 2048 + 2 * tid + j;
            pz_lds[g] = base[g * 3 + 2];
            dist[c * 2 + j] = 1e10f;
        }
    }
    if (tid == 0) {
        s_val[0] = 0u; s_val[1] = 0u; s_val[2] = 0u;
        s_idx[0] = 0x7fffffff; s_idx[1] = 0x7fffffff; s_idx[2] = 0x7fffffff;
    }
    __syncthreads();                       // pz_lds + slots ready

    int w = 1;   // RAN=False seed
    int p = 0;   // rotating slot index k%3

    for (int k = 0; k < NPOINT; ++k) {
        // Centroid: xy from ws (L2, same addr -> broadcast), z from LDS.
        const float2 cxy = xy[w];
        const float cz = pz_lds[w];
        const float cx = cxy.x, cy = cxy.y;
        if (tid == 0) {
            out_idx[(size_t)b * NPOINT + k] = (float)w;
            float* o = out_xyz + ((size_t)b * NPOINT + k) * 3;
            o[0] = cx; o[1] = cy; o[2] = cz;
        }

        // Distance update; VALUE-only tracking (fmax chain).
        float best = -1.0f;
#pragma unroll
        for (int c = 0; c < NCH; ++c) {
            const float4 v  = xy4[c * 1024 + tid];   // x0 y0 x1 y1 (L2)
            const float2 zz = *(const float2*)&pz_lds[c * 2048 + 2 * tid];
            {   // j = 0
                const float dx = v.x - cx;
                const float dy = v.y - cy;
                const float dz = zz.x - cz;
                const float d  = fmaf(dz, dz, fmaf(dx, dx, dy * dy));
                const float nd = fminf(dist[c * 2 + 0], d);
                dist[c * 2 + 0] = nd;
                best = fmaxf(best, nd);
            }
            {   // j = 1
                const float dx = v.z - cx;
                const float dy = v.w - cy;
                const float dz = zz.y - cz;
                const float d  = fmaf(dz, dz, fmaf(dx, dx, dy * dy));
                const float nd = fminf(dist[c * 2 + 1], d);
                dist[c * 2 + 1] = nd;
                best = fmaxf(best, nd);
            }
        }

        // Phase A: value-only wave max via DPP; lane 63 publishes.
        const float m = wave_max_dpp(best);
        if ((tid & 63) == 63)
            atomicMax(&s_val[p], __float_as_uint(m));
        __syncthreads();                   // B1: block max known
        const float M = __uint_as_float(s_val[p]);

        // Phase B (rare, exec-masked): candidates rescan dist[] for the
        // FIRST ==M (constant indices only) and publish the global index.
        if (best == M) {
            int li = 63;
#pragma unroll
            for (int i = 31; i >= 0; --i)
                if (dist[i] == M) li = i;          // ends at smallest i
            const int bi = (li >> 1) * 2048 + 2 * tid + (li & 1);
            atomicMin(&s_idx[p], bi);
        }
        __syncthreads();                   // B2: winning index known
        w = s_idx[p];
        // Reset slot for step k+2 (barriers of step k+1 order this write
        // before that slot's next atomics; its readers finished at k-1).
        const int pn2 = (p >= 1) ? (p - 1) : 2;   // (k+2)%3
        if (tid == 0) { s_val[pn2] = 0u; s_idx[pn2] = 0x7fffffff; }
        p = (p == 2) ? 0 : (p + 1);
    }
}

// ---------- fallback (R22-style, register xy): used only if ws too small ----
__global__ __launch_bounds__(NT, 1)
__attribute__((amdgpu_num_vgpr(128)))
void fps_fallback(
    const float* __restrict__ xyz, float* __restrict__ out_idx,
    float* __restrict__ out_xyz)
{
#pragma clang fp contract(off)
    __shared__ float pz_lds[NPTS];
    __shared__ unsigned int s_val[3];
    __shared__ int s_idx[3];
    const int b = blockIdx.x, tid = threadIdx.x;
    const float* base = xyz + (size_t)b * NPTS * 3;
    float px[NCH * 2], py[NCH * 2], dist[NCH * 2];
#pragma unroll
    for (int c = 0; c < NCH; ++c)
#pragma unroll
        for (int j = 0; j < 2; ++j) {
            const int i = c * 2 + j, g = c * 2048 + 2 * tid + j;
            px[i] = base[g * 3 + 0]; py[i] = base[g * 3 + 1];
            pz_lds[g] = base[g * 3 + 2]; dist[i] = 1e10f;
        }
    if (tid == 0) {
        s_val[0] = 0u; s_val[1] = 0u; s_val[2] = 0u;
        s_idx[0] = 0x7fffffff; s_idx[1] = 0x7fffffff; s_idx[2] = 0x7fffffff;
    }
    __syncthreads();
    int w = 1, p = 0;
    for (int k = 0; k < NPOINT; ++k) {
        const float cx = base[w * 3 + 0], cy = base[w * 3 + 1],
                    cz = base[w * 3 + 2];
        if (tid == 0) {
            out_idx[(size_t)b * NPOINT + k] = (float)w;
            float* o = out_xyz + ((size_t)b * NPOINT + k) * 3;
            o[0] = cx; o[1] = cy; o[2] = cz;
        }
        float best = -1.0f; int lc = 63;
#pragma unroll
        for (int c = 0; c < NCH; ++c) {
            const float2 zz = *(const float2*)&pz_lds[c * 2048 + 2 * tid];
            const float pzv[2] = { zz.x, zz.y };
#pragma unroll
            for (int j = 0; j < 2; ++j) {
                const int i = c * 2 + j;
                const float dx = px[i] - cx, dy = py[i] - cy,
                            dz = pzv[j] - cz;
                const float d  = fmaf(dz, dz, fmaf(dx, dx, dy * dy));
                const float nd = fminf(dist[i], d);
                dist[i] = nd;
                if (nd > best) { best = nd; lc = 2 * c + j; }
            }
        }
        const float m = wave_max_dpp(best);
        if ((tid & 63) == 63) atomicMax(&s_val[p], __float_as_uint(m));
        __syncthreads();
        const float M = __uint_as_float(s_val[p]);
        if (best == M) {
            const int bi = (lc >> 1) * 2048 + 2 * tid + (lc & 1);
            atomicMin(&s_idx[p], bi);
        }
        __syncthreads();
        w = s_idx[p];
        const int pn2 = (p >= 1) ? (p - 1) : 2;
        if (tid == 0) { s_val[pn2] = 0u; s_idx[pn2] = 0x7fffffff; }
        p = (p == 2) ? 0 : (p + 1);
    }
}

extern "C" void kernel_launch(void* const* d_in, const int* in_sizes, int n_in,
                              void* d_out, int out_size, void* d_ws, size_t ws_size,
                              hipStream_t stream) {
    const float* xyz = (const float*)d_in[0];
    float* out = (float*)d_out;
    float* out_idx = out;                              // B*NPOINT floats
    float* out_xyz = out + (size_t)BATCH * NPOINT;     // B*NPOINT*3 floats

    if (ws_size >= WS_NEEDED) {
        float2* wsxy = (float2*)d_ws;
        pack_xy<<<(BATCH * NPTS) / 256, 256, 0, stream>>>(xyz, wsxy);
        fps_kernel<<<BATCH, NT, 0, stream>>>(xyz, wsxy, out_idx, out_xyz);
    } else {
        fps_fallback<<<BATCH, NT, 0, stream>>>(xyz, out_idx, out_xyz);
    }
}